// Round 5
// baseline (191.774 us; speedup 1.0000x reference)
//
#include <hip/hip_runtime.h>

typedef __bf16 bf16;
typedef __bf16 bf16x8 __attribute__((ext_vector_type(8)));
typedef __bf16 bf16x4 __attribute__((ext_vector_type(4)));
typedef float  f32x4  __attribute__((ext_vector_type(4)));

#define D_MODEL 1024
#define S_LEN   2048
#define NHEAD   16
#define DHEAD   64
#define BATCH   2
#define MROWS   (BATCH * S_LEN)   // 4096

// 0.125 (1/sqrt(dhead)) * log2(e): Q pre-scaled so softmax runs in exp2 domain
#define QSCALE 0.18033688011112042f

// ---- async global->LDS, 16B per lane. lds_base must be wave-uniform; HW
// writes lane i's data at lds_base + i*16 (guide §5 caveat).
__device__ __forceinline__ void gld_lds16(const void* g, void* lds_base) {
    __builtin_amdgcn_global_load_lds(
        (const __attribute__((address_space(1))) void*)g,
        (__attribute__((address_space(3))) void*)lds_base, 16, 0, 0);
}

// ============= prep: transpose+cast 4 weights (z<4) | cast x (z==4) ==========
__global__ void prep_kernel(const float* __restrict__ x,
                            const float* __restrict__ W0, const float* __restrict__ W1,
                            const float* __restrict__ W2, const float* __restrict__ W3,
                            bf16* __restrict__ xb, bf16* __restrict__ Wt) {
    int tx = threadIdx.x, ty = threadIdx.y;   // (32, 8)
    if (blockIdx.z == 4) {
        int tid = ty * 32 + tx;
        size_t base = ((size_t)blockIdx.y * 32 + blockIdx.x) * 4096;
#pragma unroll
        for (int j = 0; j < 4; j++) {
            size_t i = base + (size_t)(j * 256 + tid) * 4;
            f32x4 v = *(const f32x4*)(x + i);
            bf16x4 o;
            o[0] = (bf16)v[0]; o[1] = (bf16)v[1]; o[2] = (bf16)v[2]; o[3] = (bf16)v[3];
            *(bf16x4*)(xb + i) = o;
        }
        return;
    }
    __shared__ float tile[32][33];
    const float* W = (blockIdx.z == 0) ? W0 : (blockIdx.z == 1) ? W1
                   : (blockIdx.z == 2) ? W2 : W3;
    int n0 = blockIdx.x * 32, k0 = blockIdx.y * 32;
#pragma unroll
    for (int j = 0; j < 4; j++)
        tile[ty + 8 * j][tx] = W[(size_t)(k0 + ty + 8 * j) * D_MODEL + n0 + tx];
    __syncthreads();
    bf16* out = Wt + (size_t)blockIdx.z * D_MODEL * D_MODEL;
#pragma unroll
    for (int j = 0; j < 4; j++)
        out[(size_t)(n0 + ty + 8 * j) * D_MODEL + k0 + tx] = (bf16)tile[tx][ty + 8 * j];
}

// ===================== GEMM: C[M,N] = A[M,K] @ Bt[N,K]^T + bias ==============
// m97 base + fine-vmcnt pipeline: triple-buffered LDS, prefetch depth 2,
// raw "s_waitcnt vmcnt(4); s_barrier" -> each wave waits only its own K-slab
// loads; the newest prefetch stays in flight across the barrier (no vmcnt(0)
// drain - the m97 plateau's ~20% stall).
template <int MODE>
__global__ __launch_bounds__(256, 2) void gemm_kernel(
    const bf16* __restrict__ A, const bf16* __restrict__ Bt,
    const float* __restrict__ b0, const float* __restrict__ b1, const float* __restrict__ b2,
    bf16* __restrict__ Qo, bf16* __restrict__ Ko, bf16* __restrict__ Vto,
    float* __restrict__ Co) {
    __shared__ bf16 sA[3][128 * 32];
    __shared__ bf16 sB[3][128 * 32];
    const int t = threadIdx.x;
    const int wave = t >> 6, lane = t & 63;
    const int wm = wave >> 1, wn = wave & 1;
    const int quad = lane >> 4, m16 = lane & 15;
    const int row0 = blockIdx.y * 128, col0 = blockIdx.x * 128;
    const int K = D_MODEL;
    const int NT = K / 32;   // 32 K-slabs

    f32x4 acc[4][4];
#pragma unroll
    for (int i = 0; i < 4; i++)
#pragma unroll
        for (int j = 0; j < 4; j++) acc[i][j] = (f32x4){0.f, 0.f, 0.f, 0.f};

    // stage K-slab j into buffer buf: 4 VMEM instrs per wave
    auto stage = [&](int j, int buf) {
#pragma unroll
        for (int i = 0; i < 2; i++) {
            int cb = i * 256 + wave * 64;       // wave-uniform chunk base
            int c  = cb + lane;                 // this lane's 16B chunk
            int r  = c >> 2, kg = c & 3;        // tile row, k-group
            gld_lds16(A  + (size_t)(row0 + r) * K + j * 32 + kg * 8,
                      (char*)&sA[buf][0] + cb * 16);
            gld_lds16(Bt + (size_t)(col0 + r) * K + j * 32 + kg * 8,
                      (char*)&sB[buf][0] + cb * 16);
        }
    };

    stage(0, 0);
    stage(1, 1);

    for (int j = 0; j < NT; ++j) {
        // wait own slab-j loads (leave newest prefetch in flight), then barrier
        if (j + 1 < NT) asm volatile("s_waitcnt vmcnt(4)\n\ts_barrier" ::: "memory");
        else            asm volatile("s_waitcnt vmcnt(0)\n\ts_barrier" ::: "memory");
        if (j + 2 < NT) stage(j + 2, (j + 2) % 3);   // buffer freed by barrier above
        const int cur = j % 3;

        bf16x8 af[4], bfr[4];
#pragma unroll
        for (int mi = 0; mi < 4; mi++)
            af[mi] = *(const bf16x8*)&sA[cur][(wm * 64 + mi * 16 + m16) * 32 + quad * 8];
#pragma unroll
        for (int ni = 0; ni < 4; ni++)
            bfr[ni] = *(const bf16x8*)&sB[cur][(wn * 64 + ni * 16 + m16) * 32 + quad * 8];
#pragma unroll
        for (int mi = 0; mi < 4; mi++)
#pragma unroll
            for (int ni = 0; ni < 4; ni++)
                acc[mi][ni] = __builtin_amdgcn_mfma_f32_16x16x32_bf16(
                    af[mi], bfr[ni], acc[mi][ni], 0, 0, 0);
    }

    // epilogue. C/D layout: col = lane&15, row = quad*4 + reg (m89-verified).
    if (MODE == 1) {
#pragma unroll
        for (int mi = 0; mi < 4; mi++) {
            int r0 = row0 + wm * 64 + mi * 16 + quad * 4;
#pragma unroll
            for (int ni = 0; ni < 4; ni++) {
                int col = col0 + wn * 64 + ni * 16 + m16;
                float bias = b0[col];
#pragma unroll
                for (int r = 0; r < 4; r++)
                    Co[(size_t)(r0 + r) * D_MODEL + col] = acc[mi][ni][r] + bias;
            }
        }
    } else {
        int sel = col0 >> 10;   // uniform per block (1024 % 128 == 0)
        const float* bias_arr = (sel == 0) ? b0 : (sel == 1) ? b1 : b2;
#pragma unroll
        for (int mi = 0; mi < 4; mi++) {
            int s0g = row0 + wm * 64 + mi * 16 + quad * 4;   // global M-row base
            int b = s0g >> 11, ss0 = s0g & 2047;
#pragma unroll
            for (int ni = 0; ni < 4; ni++) {
                int col = col0 + wn * 64 + ni * 16 + m16;
                int cn = col & 1023;
                int h = cn >> 6, d = cn & 63;
                float bias = bias_arr[cn];
                if (sel < 2) {
                    bf16* dst = (sel == 0) ? Qo : Ko;
                    float scl = (sel == 0) ? QSCALE : 1.0f;
                    size_t base = (((size_t)b * NHEAD + h) * S_LEN);
#pragma unroll
                    for (int r = 0; r < 4; r++)
                        dst[(base + ss0 + r) * DHEAD + d] = (bf16)((acc[mi][ni][r] + bias) * scl);
                } else {
                    bf16x4 pk;
#pragma unroll
                    for (int r = 0; r < 4; r++) pk[r] = (bf16)(acc[mi][ni][r] + bias);
                    *(bf16x4*)(Vto + (((size_t)b * NHEAD + h) * DHEAD + d) * S_LEN + ss0) = pk;
                }
            }
        }
    }
}

// ======================= flash attention (causal) ============================
// One block per (b,h, q-tile PAIR {p, 31-p}); the pair shares ONE KV stream ->
// every block does exactly 33 weighted tile-iterations (perfect balance).
// LDS diet for 3 blocks/CU (41 KB): double-buffered KV (depth-1 prefetch
// issued right after the barrier -> a full compute phase of latency cover)
// + ONE per-wave P buffer shared by both items (processed sequentially).
// Transposed scores (q = lane&15) -> per-lane softmax, no running max
// (exp2-domain |s| < ~6, fp32 exp2 overflows at 127), l reduced once at end.
__global__ __launch_bounds__(256, 3) void attn_kernel(
    const bf16* __restrict__ Q, const bf16* __restrict__ K,
    const bf16* __restrict__ Vt, bf16* __restrict__ ctx) {
    __shared__ bf16 Kt_s[2][64 * 64];
    __shared__ bf16 Vt_s[2][64 * 64];
    __shared__ bf16 P_s[4][16 * 72];   // per-wave P[q=16][kpos=64], item-shared

    const int t = threadIdx.x, wave = t >> 6, lane = t & 63;
    const int quad = lane >> 4, m16 = lane & 15;
    const int bh = blockIdx.y, p = blockIdx.x;    // pair index 0..15
    const int tT[2] = {p, 31 - p};                // item q-tiles (64 rows each)
    const int nt = 32 - p;                        // shared KV tiles (64-wide)
    const size_t base = (size_t)bh * S_LEN * DHEAD;

    // Q fragments (B-operand) for both items, kept in regs
    bf16x8 aq[2][2];
#pragma unroll
    for (int it = 0; it < 2; it++)
#pragma unroll
        for (int kst = 0; kst < 2; kst++)
            aq[it][kst] = *(const bf16x8*)(Q + base
                + (size_t)(tT[it] * 64 + wave * 16 + m16) * DHEAD + kst * 32 + quad * 8);

    f32x4 o[2][4];
#pragma unroll
    for (int it = 0; it < 2; it++)
#pragma unroll
        for (int di = 0; di < 4; di++) o[it][di] = (f32x4){0.f, 0.f, 0.f, 0.f};
    float l_acc[2] = {0.f, 0.f};

    // stage KV tile j into buffer buf (XOR chunk swizzle vs bank conflicts)
    auto stage = [&](int j, int buf) {
#pragma unroll
        for (int i = 0; i < 2; i++) {
            int cb = i * 256 + wave * 64;
            int c  = cb + lane;
            int pos = c >> 3, g = c & 7;
            int gk = g ^ (pos & 7);
            gld_lds16(K  + base + (size_t)(j * 64 + pos) * DHEAD + gk * 8,
                      (char*)&Kt_s[buf][0] + cb * 16);
            gld_lds16(Vt + base + (size_t)pos * S_LEN + j * 64 + gk * 8,
                      (char*)&Vt_s[buf][0] + cb * 16);
        }
    };

    stage(0, 0);

    for (int j = 0; j < nt; ++j) {
        // own tile-j loads done; barrier also fences buf (j+1)&1 for restaging
        asm volatile("s_waitcnt vmcnt(0)\n\ts_barrier" ::: "memory");
        if (j + 1 < nt) stage(j + 1, (j + 1) & 1);
        const int cur = j & 1;
        const bool aAct = (j <= tT[0]);   // item0 still inside its causal prefix
        const int kt0 = j * 64;

        // ---- scores S^T[kpos][q] = K @ Q^T (K-frag reads shared by items)
        f32x4 sc[2][4];
#pragma unroll
        for (int it = 0; it < 2; it++)
#pragma unroll
            for (int ni = 0; ni < 4; ni++) sc[it][ni] = (f32x4){0.f, 0.f, 0.f, 0.f};
#pragma unroll
        for (int ni = 0; ni < 4; ni++) {
            int pos = ni * 16 + m16;
#pragma unroll
            for (int kst = 0; kst < 2; kst++) {
                int gg = (kst * 4 + quad) ^ (pos & 7);
                bf16x8 kf = *(const bf16x8*)&Kt_s[cur][pos * 64 + gg * 8];
                sc[1][ni] = __builtin_amdgcn_mfma_f32_16x16x32_bf16(
                    kf, aq[1][kst], sc[1][ni], 0, 0, 0);
                if (aAct)
                    sc[0][ni] = __builtin_amdgcn_mfma_f32_16x16x32_bf16(
                        kf, aq[0][kst], sc[0][ni], 0, 0, 0);
            }
        }

        // ---- per item (sequential through the shared P buffer):
        //      mask -> exp2 -> P write -> PV MFMAs
        bf16* Pw = &P_s[wave][0];
#pragma unroll
        for (int it = 1; it >= 0; it--) {    // item1 (always active) first
            if (it == 0 && !aAct) continue;
            if (j == tT[it]) {               // diagonal tile: causal mask
                int qg = tT[it] * 64 + wave * 16 + m16;
#pragma unroll
                for (int ni = 0; ni < 4; ni++)
#pragma unroll
                    for (int r = 0; r < 4; r++) {
                        int kp = kt0 + ni * 16 + quad * 4 + r;
                        if (kp > qg) sc[it][ni][r] = -1e9f;
                    }
            }
            float ls = 0.f;
#pragma unroll
            for (int ni = 0; ni < 4; ni++) {
                bf16x4 pk;
#pragma unroll
                for (int r = 0; r < 4; r++) {
                    float pe = __builtin_amdgcn_exp2f(sc[it][ni][r]);
                    ls += pe;
                    pk[r] = (bf16)pe;
                }
                *(bf16x4*)&Pw[m16 * 72 + ni * 16 + quad * 4] = pk;
            }
            l_acc[it] += ls;
            // wave-local write->read ordering via lgkmcnt (in-order DS pipe)
#pragma unroll
            for (int kst = 0; kst < 2; kst++) {
                bf16x8 ap = *(const bf16x8*)&Pw[m16 * 72 + kst * 32 + quad * 8];
#pragma unroll
                for (int di = 0; di < 4; di++) {
                    int d = di * 16 + m16;
                    int gg = (kst * 4 + quad) ^ (d & 7);
                    bf16x8 vf = *(const bf16x8*)&Vt_s[cur][d * 64 + gg * 8];
                    o[it][di] = __builtin_amdgcn_mfma_f32_16x16x32_bf16(
                        vf, ap, o[it][di], 0, 0, 0);
                }
            }
        }
    }

    // ---- final l reduction + normalize + write ctx [B,S,1024] bf16
    int b = bh >> 4, h = bh & 15;
#pragma unroll
    for (int it = 0; it < 2; it++) {
        float l = l_acc[it];
        l += __shfl_xor(l, 16);
        l += __shfl_xor(l, 32);
        float rl = 1.0f / l;
        int s = tT[it] * 64 + wave * 16 + m16;
#pragma unroll
        for (int di = 0; di < 4; di++) {
            bf16x4 pk;
#pragma unroll
            for (int r = 0; r < 4; r++) pk[r] = (bf16)(o[it][di][r] * rl);
            *(bf16x4*)(ctx + ((size_t)b * S_LEN + s) * D_MODEL
                       + h * DHEAD + di * 16 + quad * 4) = pk;
        }
    }
}

// ================================ launch =====================================
extern "C" void kernel_launch(void* const* d_in, const int* in_sizes, int n_in,
                              void* d_out, int out_size, void* d_ws, size_t ws_size,
                              hipStream_t stream) {
    const float* x  = (const float*)d_in[0];
    const float* Wq = (const float*)d_in[1];
    const float* bq = (const float*)d_in[2];
    const float* Wk = (const float*)d_in[3];
    const float* bk = (const float*)d_in[4];
    const float* Wv = (const float*)d_in[5];
    const float* bv = (const float*)d_in[6];
    const float* Wo = (const float*)d_in[7];
    const float* bo = (const float*)d_in[8];
    float* out = (float*)d_out;

    char* ws = (char*)d_ws;
    const size_t MB = 1u << 20;
    bf16* xb  = (bf16*)(ws + 0);         // 8 MB  [4096,1024]
    bf16* Wt  = (bf16*)(ws + 8  * MB);   // 8 MB  [4][1024][1024]
    bf16* Qb  = (bf16*)(ws + 16 * MB);   // 8 MB  [B,H,S,64]  (pre-scaled by QSCALE)
    bf16* Kb  = (bf16*)(ws + 24 * MB);   // 8 MB  [B,H,S,64]
    bf16* Vtb = (bf16*)(ws + 32 * MB);   // 8 MB  [B,H,64,S]
    bf16* ctx = (bf16*)(ws + 0);         // reuse xb region (dead after QKV GEMM)

    prep_kernel<<<dim3(32, 32, 5), dim3(32, 8), 0, stream>>>(x, Wq, Wk, Wv, Wo, xb, Wt);
    gemm_kernel<0><<<dim3(24, 32), 256, 0, stream>>>(xb, Wt, bq, bk, bv,
                                                     Qb, Kb, Vtb, nullptr);
    attn_kernel<<<dim3(16, 32), 256, 0, stream>>>(Qb, Kb, Vtb, ctx);
    gemm_kernel<1><<<dim3(8, 32), 256, 0, stream>>>(ctx, Wt + 3 * 1024 * 1024,
                                                    bo, nullptr, nullptr,
                                                    nullptr, nullptr, nullptr, out);
}